// Round 8
// baseline (99.718 us; speedup 1.0000x reference)
//
#include <hip/hip_runtime.h>
#include <hip/hip_bf16.h>

// Problem constants
constexpr int NQ   = 4096;   // spatial tokens (H*W)
constexpr int NKV  = 4112;   // spatial + 16 memory tokens
constexpr int NP   = 4160;   // padded rows (65 * 64), pad is zeroed
constexpr int CDIM = 128;
constexpr int NSL  = 2;      // split-K slices (2048 keys each; slice 1 + tail)
constexpr float QSC = 0.17677669529663687f * 1.4426950408889634f; // DH^-0.5 * log2(e)

typedef __attribute__((ext_vector_type(8)))  short bf16x8;
typedef __attribute__((ext_vector_type(4)))  short bf16x4;
typedef __attribute__((ext_vector_type(4)))  float f32x4;
typedef __attribute__((ext_vector_type(16))) float f32x16;

static __device__ __forceinline__ unsigned short bfbits(float f) {
  __hip_bfloat16 h = __float2bfloat16(f);
  return *reinterpret_cast<unsigned short*>(&h);
}
static __device__ __forceinline__ unsigned pk2(float a, float b) {
  return (unsigned)bfbits(a) | ((unsigned)bfbits(b) << 16);
}

// ---------------- Kernel 1: QKV projection (+ w_out cast) ----------------
// grid (65, 4 batches), block 512 (8 waves, 3 o-tiles each -> 2 waves/SIMD).
//   Qt[bh][n][d] (bf16, pre-scaled by QSC), Kt[bh][n][d], Vt[bh][d][n]
__global__ __launch_bounds__(512) void k1_qkv(
    const float* __restrict__ x, const float* __restrict__ memry,
    const float* __restrict__ wqkv, const float* __restrict__ wout,
    __hip_bfloat16* __restrict__ Qt, __hip_bfloat16* __restrict__ Kt,
    __hip_bfloat16* __restrict__ Vt, __hip_bfloat16* __restrict__ Wb) {
  __shared__ __align__(16) __hip_bfloat16 xt[64][136];  // [n-local][c], +8 pad
  const int b  = blockIdx.y;
  const int nb = blockIdx.x * 64;
  const int t  = threadIdx.x;
  const int wv = t >> 6, ln = t & 63;          // wv 0..7

  if (blockIdx.x == 0 && b == 0) {
    for (int i = t; i < CDIM * CDIM; i += 512) Wb[i] = __float2bfloat16(wout[i]);
  }

  { // stage x_ext tile (transposed, bf16); wave wv covers c = wv*16 .. +16
    const int n = nb + ln;
    #pragma unroll
    for (int i = 0; i < 8; ++i) {
      const int c = wv * 16 + 2 * i;
      float v0 = 0.f, v1 = 0.f;
      if (n < NQ)        { v0 = x[((size_t)b * CDIM + c) * NQ + n];
                           v1 = x[((size_t)b * CDIM + c + 1) * NQ + n]; }
      else if (n < NKV)  { v0 = memry[c * 16 + (n - NQ)];
                           v1 = memry[(c + 1) * 16 + (n - NQ)]; }
      *reinterpret_cast<unsigned*>(&xt[ln][c]) =
          (unsigned)bfbits(v0) | ((unsigned)bfbits(v1) << 16);
    }
  }
  __syncthreads();

  const int li = ln & 15, g = ln >> 4;
  bf16x8 xa[4][4];
  #pragma unroll
  for (int nt = 0; nt < 4; ++nt)
    #pragma unroll
    for (int k = 0; k < 4; ++k)
      xa[nt][k] = *reinterpret_cast<const bf16x8*>(&xt[nt * 16 + li][k * 32 + 8 * g]);

  #pragma unroll
  for (int oi = 0; oi < 3; ++oi) {
    const int ot = wv * 3 + oi;                 // 24 o-tiles: 0-7 Q, 8-15 K, 16-23 V
    bf16x8 wf[4];
    #pragma unroll
    for (int k = 0; k < 4; ++k) {
      const float* wp = &wqkv[(size_t)(ot * 16 + li) * CDIM + k * 32 + 8 * g];
      const float4 f0 = *reinterpret_cast<const float4*>(wp);
      const float4 f1 = *reinterpret_cast<const float4*>(wp + 4);
      bf16x8 wc;
      wc[0] = (short)bfbits(f0.x); wc[1] = (short)bfbits(f0.y);
      wc[2] = (short)bfbits(f0.z); wc[3] = (short)bfbits(f0.w);
      wc[4] = (short)bfbits(f1.x); wc[5] = (short)bfbits(f1.y);
      wc[6] = (short)bfbits(f1.z); wc[7] = (short)bfbits(f1.w);
      wf[k] = wc;
    }
    #pragma unroll
    for (int nt = 0; nt < 4; ++nt) {
      f32x4 a; a[0] = a[1] = a[2] = a[3] = 0.f;
      if (ot < 16) {
        // D[row=n][col=o]  (A = x-tile, B = W^T)
        #pragma unroll
        for (int k = 0; k < 4; ++k)
          a = __builtin_amdgcn_mfma_f32_16x16x32_bf16(xa[nt][k], wf[k], a, 0, 0, 0);
        const int o = ot * 16 + li;
        const int h = (o >> 5) & 3, d = o & 31;
        if (ot < 8) {
          #pragma unroll
          for (int r = 0; r < 4; ++r) {
            const int n = nb + nt * 16 + 4 * g + r;
            Qt[((size_t)(b * 4 + h) * NP + n) * 32 + d] = __float2bfloat16(a[r] * QSC);
          }
        } else {
          #pragma unroll
          for (int r = 0; r < 4; ++r) {
            const int n = nb + nt * 16 + 4 * g + r;
            Kt[((size_t)(b * 4 + h) * NP + n) * 32 + d] = __float2bfloat16(a[r]);
          }
        }
      } else {
        // D[row=o][col=n]  (A = W, B = x-tile)
        #pragma unroll
        for (int k = 0; k < 4; ++k)
          a = __builtin_amdgcn_mfma_f32_16x16x32_bf16(wf[k], xa[nt][k], a, 0, 0, 0);
        #pragma unroll
        for (int r = 0; r < 4; ++r) {
          const int o = ot * 16 + 4 * g + r;
          const int h = (o >> 5) & 3, d = o & 31;
          const int n = nb + nt * 16 + li;
          Vt[((size_t)(b * 4 + h) * 32 + d) * NP + n] = __float2bfloat16(a[r]);
        }
      }
    }
  }
}

// ---- Kernel 2: attention partials; XCD-pinned, LDS dbuf + XOR swizzle ----
// Swizzle (verified write<->read consistent): 16B slot at byte B moves to
// B ^ (((B>>7)&7)<<4). V-region 8B granules additionally XOR bit3 with row&1,
// implemented as a conditional half-swap on the 16B write. Kills the 4-way
// K/V bank conflicts (4.2M/dispatch in round 7).
// grid 1024 flat blocks, block 256 = 4 waves, 32 q per wave.

#if __has_builtin(__builtin_amdgcn_mfma_f32_32x32x8bf16_1k)
#define HAS_PV8 1
#else
#define HAS_PV8 0
#endif

__global__ __launch_bounds__(256, 4) void k2_attn(
    const __hip_bfloat16* __restrict__ Qt, const __hip_bfloat16* __restrict__ Kt,
    const __hip_bfloat16* __restrict__ Vt, float* __restrict__ Pb,
    float* __restrict__ Lb) {
  // two 8KB staging buffers: [K 4KB | V 4KB] each, fragment-ordered + swizzled
  __shared__ __align__(16) unsigned char smem[16384];

  // XCD-pinned decomposition (assumes xcd = blockIdx % 8; perf-only heuristic)
  const int wg  = blockIdx.x;          // 0..1023
  const int xcd = wg & 7;
  const int i   = wg >> 3;             // 0..127
  const int bh  = 2 * xcd + (i & 1);   // 2 bh per XCD
  const int sl  = (i >> 1) & 1;        // split-K slice
  const int wv  = threadIdx.x >> 6, lane = threadIdx.x & 63;
  const int lq  = lane & 31, hi = lane >> 5;
  const int qb  = (i >> 2) * 128 + wv * 32;

  const bf16x8 qf0 = *reinterpret_cast<const bf16x8*>(
      Qt + ((size_t)bh * NP + qb + lq) * 32 + 8 * hi);
  const bf16x8 qf1 = *reinterpret_cast<const bf16x8*>(
      Qt + ((size_t)bh * NP + qb + lq) * 32 + 16 + 8 * hi);

  // Staging sources: wave wv owns chunk c=wv (1KB) of the K-tile and V-tile.
  const int kb0 = sl * 2048;
  const __hip_bfloat16* Ksrc = Kt + ((size_t)bh * NP + kb0 + (wv >> 1) * 32 + lq) * 32
                                  + (wv & 1) * 16 + 8 * hi;
  const __hip_bfloat16* Vsrc = Vt + ((size_t)bh * 32 + lq) * NP + kb0 + wv * 16 + 8 * hi;

  // swizzled LDS offsets (loop-invariant)
  const int rowb  = (lane >> 3) & 7;               // write row
  const int wswz  = (wv * 1024 + lane * 16) ^ (rowb << 4);
  const bool vswap = rowb & 1;
  const int krb   = lq * 16 + hi * 512;
  const int krswz = krb ^ (((krb >> 7) & 7) << 4); // K read base (kf0 st=0)
  int voff[4];
  #pragma unroll
  for (int j = 0; j < 4; ++j) {
    const int vb_ = j * 512 + lq * 16 + hi * 8;
    const int r_  = (vb_ >> 7) & 7;
    voff[j] = vb_ ^ (r_ << 4) ^ ((r_ & 1) << 3);
  }

  f32x16 acc0, acc1, z;
  #pragma unroll
  for (int q = 0; q < 16; ++q) { acc0[q] = 0.f; acc1[q] = 0.f; z[q] = 0.f; }
  float l0 = 0.f, l1 = 0.f, l2 = 0.f, l3 = 0.f;

  bf16x8 kreg = *reinterpret_cast<const bf16x8*>(Ksrc);
  bf16x8 vreg = *reinterpret_cast<const bf16x8*>(Vsrc);

#define WRITE_KV(basep)                                                        \
  {                                                                            \
    *reinterpret_cast<bf16x8*>((basep) + wswz) = kreg;                         \
    bf16x8 vv;                                                                 \
    vv[0] = vreg[4]; vv[1] = vreg[5]; vv[2] = vreg[6]; vv[3] = vreg[7];        \
    vv[4] = vreg[0]; vv[5] = vreg[1]; vv[6] = vreg[2]; vv[7] = vreg[3];        \
    *reinterpret_cast<bf16x8*>((basep) + 4096 + wswz) = vswap ? vv : vreg;     \
  }

  // prologue: tile 0 -> buf0; tile 1 loads in flight
  WRITE_KV(smem)
  kreg = *reinterpret_cast<const bf16x8*>(Ksrc + 2048);
  vreg = *reinterpret_cast<const bf16x8*>(Vsrc + 64);

  for (int t = 0; t < 32; ++t) {
    __syncthreads();   // buf[t&1] ready (written last iter, drained by barrier)
    const int p = t & 1;
    if (t < 31) {      // stage tile t+1 into the idle buffer
      unsigned char* nbuf = smem + (p ^ 1) * 8192;
      WRITE_KV(nbuf)
      if (t < 30) {    // issue loads for tile t+2
        kreg = *reinterpret_cast<const bf16x8*>(Ksrc + (size_t)(t + 2) * 2048);
        vreg = *reinterpret_cast<const bf16x8*>(Vsrc + (t + 2) * 64);
      }
    }
    const unsigned char* bufb = smem + p * 8192;

    #pragma unroll
    for (int st = 0; st < 2; ++st) {           // two 32-key subtiles
      const bf16x8 kf0 = *reinterpret_cast<const bf16x8*>(bufb + st * 2048 + krswz);
      const bf16x8 kf1 = *reinterpret_cast<const bf16x8*>(bufb + st * 2048 + 1024 + krswz);
      f32x16 s = __builtin_amdgcn_mfma_f32_32x32x16_bf16(kf0, qf0, z, 0, 0, 0);
      s = __builtin_amdgcn_mfma_f32_32x32x16_bf16(kf1, qf1, s, 0, 0, 0);
      float p_[16];
      #pragma unroll
      for (int r = 0; r < 16; ++r) p_[r] = __builtin_amdgcn_exp2f(s[r]);
      l0 += (p_[0] + p_[1]) + (p_[2] + p_[3]);
      l1 += (p_[4] + p_[5]) + (p_[6] + p_[7]);
      l2 += (p_[8] + p_[9]) + (p_[10] + p_[11]);
      l3 += (p_[12] + p_[13]) + (p_[14] + p_[15]);
#if HAS_PV8
      union UU { unsigned u[2]; bf16x4 v; };
      UU a0, a1, a2, a3;  // quad r -> keys {0,8,16,24} + 4*hi + 0..3
      a0.u[0] = pk2(p_[0], p_[1]);   a0.u[1] = pk2(p_[2], p_[3]);
      a1.u[0] = pk2(p_[4], p_[5]);   a1.u[1] = pk2(p_[6], p_[7]);
      a2.u[0] = pk2(p_[8], p_[9]);   a2.u[1] = pk2(p_[10], p_[11]);
      a3.u[0] = pk2(p_[12], p_[13]); a3.u[1] = pk2(p_[14], p_[15]);
      const unsigned char* vb = bufb + 4096 + st * 2048;
      const bf16x4 vf0 = *reinterpret_cast<const bf16x4*>(vb + voff[0]);
      const bf16x4 vf1 = *reinterpret_cast<const bf16x4*>(vb + voff[1]);
      const bf16x4 vf2 = *reinterpret_cast<const bf16x4*>(vb + voff[2]);
      const bf16x4 vf3 = *reinterpret_cast<const bf16x4*>(vb + voff[3]);
      acc0 = __builtin_amdgcn_mfma_f32_32x32x8bf16_1k(a0.v, vf0, acc0, 0, 0, 0);
      acc0 = __builtin_amdgcn_mfma_f32_32x32x8bf16_1k(a1.v, vf1, acc0, 0, 0, 0);
      acc1 = __builtin_amdgcn_mfma_f32_32x32x8bf16_1k(a2.v, vf2, acc1, 0, 0, 0);
      acc1 = __builtin_amdgcn_mfma_f32_32x32x8bf16_1k(a3.v, vf3, acc1, 0, 0, 0);
#else
      unsigned a0u0 = pk2(p_[0], p_[1]),   a0u1 = pk2(p_[2], p_[3]);
      unsigned a1u0 = pk2(p_[4], p_[5]),   a1u1 = pk2(p_[6], p_[7]);
      unsigned a2u0 = pk2(p_[8], p_[9]),   a2u1 = pk2(p_[10], p_[11]);
      unsigned a3u0 = pk2(p_[12], p_[13]), a3u1 = pk2(p_[14], p_[15]);
      union U8 { unsigned u[4]; bf16x8 v; };
      // fallback path keeps the round-6 (unswizzled) V layout reads via the
      // swizzled 16B slots: reconstruct from two b64 halves
      const unsigned char* vb = bufb + 4096 + st * 2048;
      union { bf16x4 h[2]; bf16x8 w; } vh0, vh1;
      vh0.h[0] = *reinterpret_cast<const bf16x4*>(vb + voff[0]);
      vh0.h[1] = *reinterpret_cast<const bf16x4*>(vb + voff[1]);
      vh1.h[0] = *reinterpret_cast<const bf16x4*>(vb + voff[2]);
      vh1.h[1] = *reinterpret_cast<const bf16x4*>(vb + voff[3]);
      {
        const unsigned s0 = __shfl_xor(hi ? a0u0 : a1u0, 32, 64);
        const unsigned s1 = __shfl_xor(hi ? a0u1 : a1u1, 32, 64);
        U8 f;
        f.u[0] = hi ? s0 : a0u0; f.u[1] = hi ? s1 : a0u1;
        f.u[2] = hi ? a1u0 : s0; f.u[3] = hi ? a1u1 : s1;
        acc0 = __builtin_amdgcn_mfma_f32_32x32x16_bf16(f.v, vh0.w, acc0, 0, 0, 0);
      }
      {
        const unsigned s0 = __shfl_xor(hi ? a2u0 : a3u0, 32, 64);
        const unsigned s1 = __shfl_xor(hi ? a2u1 : a3u1, 32, 64);
        U8 f;
        f.u[0] = hi ? s0 : a2u0; f.u[1] = hi ? s1 : a2u1;
        f.u[2] = hi ? a3u0 : s0; f.u[3] = hi ? a3u1 : s1;
        acc1 = __builtin_amdgcn_mfma_f32_32x32x16_bf16(f.v, vh1.w, acc1, 0, 0, 0);
      }
#endif
    }
  }
#undef WRITE_KV

  if (sl == NSL - 1) {
    // tail: 16 real keys (4096..4111), direct from global (L2-hot, tiny)
    const __hip_bfloat16* Kp   = Kt + (size_t)bh * NP * 32 + (size_t)lq * 32 + 8 * hi;
    const __hip_bfloat16* Vrow = Vt + ((size_t)bh * 32 + lq) * NP;
    const int kb = 4096;
    const bf16x8 kf0 = *reinterpret_cast<const bf16x8*>(Kp + (size_t)kb * 32);
    const bf16x8 kf1 = *reinterpret_cast<const bf16x8*>(Kp + (size_t)kb * 32 + 16);
    f32x16 s = __builtin_amdgcn_mfma_f32_32x32x16_bf16(kf0, qf0, z, 0, 0, 0);
    s = __builtin_amdgcn_mfma_f32_32x32x16_bf16(kf1, qf1, s, 0, 0, 0);
    float p_[8];
    #pragma unroll
    for (int r = 0; r < 8; ++r) p_[r] = __builtin_amdgcn_exp2f(s[r]);
    l0 += (p_[0] + p_[1]) + (p_[2] + p_[3]);
    l1 += (p_[4] + p_[5]) + (p_[6] + p_[7]);
#if HAS_PV8
    union UU { unsigned u[2]; bf16x4 v; };
    UU a0, a1;
    a0.u[0] = pk2(p_[0], p_[1]); a0.u[1] = pk2(p_[2], p_[3]);
    a1.u[0] = pk2(p_[4], p_[5]); a1.u[1] = pk2(p_[6], p_[7]);
    const bf16x4 vf0 = *reinterpret_cast<const bf16x4*>(Vrow + kb + 4 * hi);
    const bf16x4 vf1 = *reinterpret_cast<const bf16x4*>(Vrow + kb + 8 + 4 * hi);
    acc0 = __builtin_amdgcn_mfma_f32_32x32x8bf16_1k(a0.v, vf0, acc0, 0, 0, 0);
    acc0 = __builtin_amdgcn_mfma_f32_32x32x8bf16_1k(a1.v, vf1, acc0, 0, 0, 0);
#else
    unsigned a0u0 = pk2(p_[0], p_[1]), a0u1 = pk2(p_[2], p_[3]);
    unsigned a1u0 = pk2(p_[4], p_[5]), a1u1 = pk2(p_[6], p_[7]);
    union U8 { unsigned u[4]; bf16x8 v; };
    const unsigned s0 = __shfl_xor(hi ? a0u0 : a1u0, 32, 64);
    const unsigned s1 = __shfl_xor(hi ? a0u1 : a1u1, 32, 64);
    U8 f;
    f.u[0] = hi ? s0 : a0u0; f.u[1] = hi ? s1 : a0u1;
    f.u[2] = hi ? a1u0 : s0; f.u[3] = hi ? a1u1 : s1;
    const bf16x8 vf = *reinterpret_cast<const bf16x8*>(Vrow + kb + 8 * hi);
    acc0 = __builtin_amdgcn_mfma_f32_32x32x16_bf16(f.v, vf, acc0, 0, 0, 0);
#endif
  }

  // write partials: P[sl][bh][q][d] (d = lq), L[sl][bh][q]
  float* Pp = Pb + (((size_t)sl * 16 + bh) * NQ + qb) * 32;
  #pragma unroll
  for (int r = 0; r < 16; ++r) {
    const int q = (r & 3) + 8 * (r >> 2) + 4 * hi;
    Pp[(size_t)q * 32 + lq] = acc0[r] + acc1[r];
  }
  float lsum = (l0 + l1) + (l2 + l3);       // partial for q = lq (this hi)
  lsum += __shfl_xor(lsum, 32, 64);
  if (hi == 0)
    Lb[((size_t)sl * 16 + bh) * NQ + qb + lq] = lsum;
}

// ------- Kernel 3: output projection, fused split-K combine -------
// grid (64 n-tiles, 4 batches), block 512 (8 waves, 1 o-tile each).
// bfr fragments built from P slices: (P0 + P1) * inv, inv = 1/(L0+L1).
__global__ __launch_bounds__(512) void k3_proj(
    const float* __restrict__ Pb, const float* __restrict__ Lb,
    const __hip_bfloat16* __restrict__ Wb, const float* __restrict__ bout,
    float* __restrict__ out) {
  const int b = blockIdx.y, nb = blockIdx.x * 64;
  const int wv = threadIdx.x >> 6;           // 0..7 = o-tile
  const int lane = threadIdx.x & 63;
  const int li = lane & 15, g = lane >> 4;
  constexpr size_t PS = (size_t)16 * NQ * 32;
  constexpr size_t LS = (size_t)16 * NQ;

  bf16x8 wf[4];
  float bo[4];
  #pragma unroll
  for (int k = 0; k < 4; ++k)
    wf[k] = *reinterpret_cast<const bf16x8*>(
        &Wb[(size_t)(wv * 16 + li) * CDIM + k * 32 + 8 * g]);
  #pragma unroll
  for (int r = 0; r < 4; ++r) bo[r] = bout[wv * 16 + 4 * g + r];

  #pragma unroll
  for (int nt = 0; nt < 4; ++nt) {
    const int q = nb + nt * 16 + li;
    bf16x8 bfr[4];
    #pragma unroll
    for (int k = 0; k < 4; ++k) {
      const size_t qi = (size_t)(b * 4 + k) * NQ + q;
      const float inv = 1.f / (Lb[qi] + Lb[LS + qi]);
      const float* pp = Pb + qi * 32 + 8 * g;
      const float4 a0 = *reinterpret_cast<const float4*>(pp);
      const float4 a1 = *reinterpret_cast<const float4*>(pp + 4);
      const float4 c0 = *reinterpret_cast<const float4*>(pp + PS);
      const float4 c1 = *reinterpret_cast<const float4*>(pp + PS + 4);
      bf16x8 fr;
      fr[0] = (short)bfbits((a0.x + c0.x) * inv);
      fr[1] = (short)bfbits((a0.y + c0.y) * inv);
      fr[2] = (short)bfbits((a0.z + c0.z) * inv);
      fr[3] = (short)bfbits((a0.w + c0.w) * inv);
      fr[4] = (short)bfbits((a1.x + c1.x) * inv);
      fr[5] = (short)bfbits((a1.y + c1.y) * inv);
      fr[6] = (short)bfbits((a1.z + c1.z) * inv);
      fr[7] = (short)bfbits((a1.w + c1.w) * inv);
      bfr[k] = fr;
    }
    f32x4 a; a[0] = a[1] = a[2] = a[3] = 0.f;
    #pragma unroll
    for (int k = 0; k < 4; ++k)
      a = __builtin_amdgcn_mfma_f32_16x16x32_bf16(wf[k], bfr[k], a, 0, 0, 0);
    #pragma unroll
    for (int r = 0; r < 4; ++r)
      out[((size_t)b * CDIM + wv * 16 + 4 * g + r) * NQ + nb + nt * 16 + li] =
          a[r] + bo[r];
  }
}

extern "C" void kernel_launch(void* const* d_in, const int* in_sizes, int n_in,
                              void* d_out, int out_size, void* d_ws, size_t ws_size,
                              hipStream_t stream) {
  const float* x    = (const float*)d_in[0];
  const float* memp = (const float*)d_in[1];
  const float* wqkv = (const float*)d_in[2];
  const float* wout = (const float*)d_in[3];
  const float* bout = (const float*)d_in[4];
  float* out = (float*)d_out;

  char* ws = (char*)d_ws;
  const size_t SZ  = (size_t)16 * NP * 32 * 2;              // Qt/Kt/Vt each
  const size_t PSZ = (size_t)NSL * 16 * NQ * 32 * 4;        // 16.8 MB
  const size_t LSZ = (size_t)NSL * 16 * NQ * 4;             // 0.5 MB
  __hip_bfloat16* Qt  = (__hip_bfloat16*)(ws);
  __hip_bfloat16* Kt  = (__hip_bfloat16*)(ws + SZ);
  __hip_bfloat16* Vt  = (__hip_bfloat16*)(ws + 2 * SZ);
  float*          Pbf = (float*)(ws + 3 * SZ);
  float*          Lbf = (float*)(ws + 3 * SZ + PSZ);
  __hip_bfloat16* Wb  = (__hip_bfloat16*)(ws + 3 * SZ + PSZ + LSZ);

  hipLaunchKernelGGL(k1_qkv, dim3(65, 4), dim3(512), 0, stream,
                     x, memp, wqkv, wout, Qt, Kt, Vt, Wb);
  hipLaunchKernelGGL(k2_attn, dim3(1024), dim3(256), 0, stream,
                     Qt, Kt, Vt, Pbf, Lbf);
  hipLaunchKernelGGL(k3_proj, dim3(64, 4), dim3(512), 0, stream,
                     Pbf, Lbf, Wb, bout, out);
}

// Round 9
// 94.623 us; speedup vs baseline: 1.0538x; 1.0538x over previous
//
#include <hip/hip_runtime.h>
#include <hip/hip_bf16.h>

// Problem constants
constexpr int NQ   = 4096;   // spatial tokens (H*W)
constexpr int NKV  = 4112;   // spatial + 16 memory tokens
constexpr int NP   = 4160;   // padded rows (65 * 64), pad is zeroed
constexpr int CDIM = 128;
constexpr int NSL  = 4;      // split-K slices (1024 keys each; slice 3 + tail)
constexpr float QSC = 0.17677669529663687f * 1.4426950408889634f; // DH^-0.5 * log2(e)

typedef __attribute__((ext_vector_type(8)))  short bf16x8;
typedef __attribute__((ext_vector_type(4)))  short bf16x4;
typedef __attribute__((ext_vector_type(4)))  float f32x4;
typedef __attribute__((ext_vector_type(16))) float f32x16;

static __device__ __forceinline__ unsigned short bfbits(float f) {
  __hip_bfloat16 h = __float2bfloat16(f);
  return *reinterpret_cast<unsigned short*>(&h);
}
static __device__ __forceinline__ unsigned pk2(float a, float b) {
  return (unsigned)bfbits(a) | ((unsigned)bfbits(b) << 16);
}

// ---------------- Kernel 1: QKV projection (+ w_out cast) ----------------
// grid (65, 4 batches, 2 o-halves), block 256 (4 waves, 3 o-tiles each).
//   Qt[bh][n][d] (bf16, pre-scaled by QSC), Kt[bh][n][d], Vt[bh][d][n]
__global__ __launch_bounds__(256) void k1_qkv(
    const float* __restrict__ x, const float* __restrict__ memry,
    const float* __restrict__ wqkv, const float* __restrict__ wout,
    __hip_bfloat16* __restrict__ Qt, __hip_bfloat16* __restrict__ Kt,
    __hip_bfloat16* __restrict__ Vt, __hip_bfloat16* __restrict__ Wb) {
  __shared__ __align__(16) __hip_bfloat16 xt[64][136];  // [n-local][c], +8 pad
  const int b  = blockIdx.y;
  const int zz = blockIdx.z;                   // o-half: 0 -> tiles 0-11, 1 -> 12-23
  const int nb = blockIdx.x * 64;
  const int t  = threadIdx.x;
  const int wv = t >> 6, ln = t & 63;

  if (blockIdx.x == 0 && b == 0 && zz == 0) {
    for (int i = t; i < CDIM * CDIM; i += 256) Wb[i] = __float2bfloat16(wout[i]);
  }

  { // stage x_ext tile (transposed, bf16)
    const int n = nb + ln;
    #pragma unroll
    for (int i = 0; i < 16; ++i) {
      const int c = wv * 32 + 2 * i;
      float v0 = 0.f, v1 = 0.f;
      if (n < NQ)        { v0 = x[((size_t)b * CDIM + c) * NQ + n];
                           v1 = x[((size_t)b * CDIM + c + 1) * NQ + n]; }
      else if (n < NKV)  { v0 = memry[c * 16 + (n - NQ)];
                           v1 = memry[(c + 1) * 16 + (n - NQ)]; }
      *reinterpret_cast<unsigned*>(&xt[ln][c]) =
          (unsigned)bfbits(v0) | ((unsigned)bfbits(v1) << 16);
    }
  }
  __syncthreads();

  const int li = ln & 15, g = ln >> 4;
  bf16x8 xa[4][4];
  #pragma unroll
  for (int nt = 0; nt < 4; ++nt)
    #pragma unroll
    for (int k = 0; k < 4; ++k)
      xa[nt][k] = *reinterpret_cast<const bf16x8*>(&xt[nt * 16 + li][k * 32 + 8 * g]);

  #pragma unroll
  for (int oi = 0; oi < 3; ++oi) {
    const int ot = zz * 12 + wv * 3 + oi;       // 24 o-tiles: 0-7 Q, 8-15 K, 16-23 V
    bf16x8 wf[4];
    #pragma unroll
    for (int k = 0; k < 4; ++k) {
      const float* wp = &wqkv[(size_t)(ot * 16 + li) * CDIM + k * 32 + 8 * g];
      const float4 f0 = *reinterpret_cast<const float4*>(wp);
      const float4 f1 = *reinterpret_cast<const float4*>(wp + 4);
      bf16x8 wc;
      wc[0] = (short)bfbits(f0.x); wc[1] = (short)bfbits(f0.y);
      wc[2] = (short)bfbits(f0.z); wc[3] = (short)bfbits(f0.w);
      wc[4] = (short)bfbits(f1.x); wc[5] = (short)bfbits(f1.y);
      wc[6] = (short)bfbits(f1.z); wc[7] = (short)bfbits(f1.w);
      wf[k] = wc;
    }
    #pragma unroll
    for (int nt = 0; nt < 4; ++nt) {
      f32x4 a; a[0] = a[1] = a[2] = a[3] = 0.f;
      if (ot < 16) {
        // D[row=n][col=o]  (A = x-tile, B = W^T)
        #pragma unroll
        for (int k = 0; k < 4; ++k)
          a = __builtin_amdgcn_mfma_f32_16x16x32_bf16(xa[nt][k], wf[k], a, 0, 0, 0);
        const int o = ot * 16 + li;
        const int h = (o >> 5) & 3, d = o & 31;
        if (ot < 8) {
          #pragma unroll
          for (int r = 0; r < 4; ++r) {
            const int n = nb + nt * 16 + 4 * g + r;
            Qt[((size_t)(b * 4 + h) * NP + n) * 32 + d] = __float2bfloat16(a[r] * QSC);
          }
        } else {
          #pragma unroll
          for (int r = 0; r < 4; ++r) {
            const int n = nb + nt * 16 + 4 * g + r;
            Kt[((size_t)(b * 4 + h) * NP + n) * 32 + d] = __float2bfloat16(a[r]);
          }
        }
      } else {
        // D[row=o][col=n]  (A = W, B = x-tile)
        #pragma unroll
        for (int k = 0; k < 4; ++k)
          a = __builtin_amdgcn_mfma_f32_16x16x32_bf16(wf[k], xa[nt][k], a, 0, 0, 0);
        #pragma unroll
        for (int r = 0; r < 4; ++r) {
          const int o = ot * 16 + 4 * g + r;
          const int h = (o >> 5) & 3, d = o & 31;
          const int n = nb + nt * 16 + li;
          Vt[((size_t)(b * 4 + h) * 32 + d) * NP + n] = __float2bfloat16(a[r]);
        }
      }
    }
  }
}

// ---- Kernel 2: attention partials; XCD-pinned, LDS dbuf, split-K x4 ----
// 64 VGPR -> 8 blocks/CU (32 waves/CU) with 16KB LDS each. Round-7 body
// (un-swizzled: conflicts measured off-critical-path), NSL=4 for occupancy.
// grid 2048 flat blocks, block 256 = 4 waves, 32 q per wave.

#if __has_builtin(__builtin_amdgcn_mfma_f32_32x32x8bf16_1k)
#define HAS_PV8 1
#else
#define HAS_PV8 0
#endif

__global__ __launch_bounds__(256, 4) void k2_attn(
    const __hip_bfloat16* __restrict__ Qt, const __hip_bfloat16* __restrict__ Kt,
    const __hip_bfloat16* __restrict__ Vt, float* __restrict__ Pb,
    float* __restrict__ Lb) {
  // two 8KB staging buffers: [K 4KB | V 4KB] each, fragment-ordered
  __shared__ __align__(16) unsigned char smem[16384];

  // XCD-pinned decomposition (assumes xcd = blockIdx % 8; perf-only heuristic)
  const int wg  = blockIdx.x;          // 0..2047
  const int xcd = wg & 7;
  const int i   = wg >> 3;             // 0..255
  const int bh  = 2 * xcd + (i & 1);   // 2 bh per XCD
  const int sl  = (i >> 1) & 3;        // split-K slice 0..3
  const int wv  = threadIdx.x >> 6, lane = threadIdx.x & 63;
  const int lq  = lane & 31, hi = lane >> 5;
  const int qb  = (i >> 3) * 128 + wv * 32;

  const bf16x8 qf0 = *reinterpret_cast<const bf16x8*>(
      Qt + ((size_t)bh * NP + qb + lq) * 32 + 8 * hi);
  const bf16x8 qf1 = *reinterpret_cast<const bf16x8*>(
      Qt + ((size_t)bh * NP + qb + lq) * 32 + 16 + 8 * hi);

  // Staging sources: wave wv owns chunk c=wv (1KB) of the K-tile and V-tile.
  const int kb0 = sl * 1024;
  const __hip_bfloat16* Ksrc = Kt + ((size_t)bh * NP + kb0 + (wv >> 1) * 32 + lq) * 32
                                  + (wv & 1) * 16 + 8 * hi;
  const __hip_bfloat16* Vsrc = Vt + ((size_t)bh * 32 + lq) * NP + kb0 + wv * 16 + 8 * hi;
  const int dstoff = wv * 1024 + lane * 16;    // byte offset within K/V region

  f32x16 acc0, acc1, z;
  #pragma unroll
  for (int q = 0; q < 16; ++q) { acc0[q] = 0.f; acc1[q] = 0.f; z[q] = 0.f; }
  float l0 = 0.f, l1 = 0.f, l2 = 0.f, l3 = 0.f;

  // prologue: tile 0 -> buf0; tile 1 loads in flight
  bf16x8 kreg = *reinterpret_cast<const bf16x8*>(Ksrc);
  bf16x8 vreg = *reinterpret_cast<const bf16x8*>(Vsrc);
  *reinterpret_cast<bf16x8*>(smem + dstoff)        = kreg;
  *reinterpret_cast<bf16x8*>(smem + 4096 + dstoff) = vreg;
  kreg = *reinterpret_cast<const bf16x8*>(Ksrc + 2048);
  vreg = *reinterpret_cast<const bf16x8*>(Vsrc + 64);

  for (int t = 0; t < 16; ++t) {
    __syncthreads();   // buf[t&1] ready; compute on buf[(t+1)&1] drained
    const int p = t & 1;
    if (t < 15) {      // stage tile t+1 into the idle buffer
      unsigned char* nbuf = smem + (p ^ 1) * 8192;
      *reinterpret_cast<bf16x8*>(nbuf + dstoff)        = kreg;
      *reinterpret_cast<bf16x8*>(nbuf + 4096 + dstoff) = vreg;
      if (t < 14) {    // issue loads for tile t+2
        kreg = *reinterpret_cast<const bf16x8*>(Ksrc + (size_t)(t + 2) * 2048);
        vreg = *reinterpret_cast<const bf16x8*>(Vsrc + (t + 2) * 64);
      }
    }
    const __hip_bfloat16* kbuf = (const __hip_bfloat16*)(smem + p * 8192);
    const __hip_bfloat16* vbuf = (const __hip_bfloat16*)(smem + p * 8192 + 4096);

    #pragma unroll
    for (int st = 0; st < 2; ++st) {           // two 32-key subtiles
      const bf16x8 kf0 = *reinterpret_cast<const bf16x8*>(kbuf + st * 1024 + lane * 8);
      const bf16x8 kf1 = *reinterpret_cast<const bf16x8*>(kbuf + st * 1024 + 512 + lane * 8);
      f32x16 s = __builtin_amdgcn_mfma_f32_32x32x16_bf16(kf0, qf0, z, 0, 0, 0);
      s = __builtin_amdgcn_mfma_f32_32x32x16_bf16(kf1, qf1, s, 0, 0, 0);
      float p_[16];
      #pragma unroll
      for (int r = 0; r < 16; ++r) p_[r] = __builtin_amdgcn_exp2f(s[r]);
      l0 += (p_[0] + p_[1]) + (p_[2] + p_[3]);
      l1 += (p_[4] + p_[5]) + (p_[6] + p_[7]);
      l2 += (p_[8] + p_[9]) + (p_[10] + p_[11]);
      l3 += (p_[12] + p_[13]) + (p_[14] + p_[15]);
#if HAS_PV8
      union UU { unsigned u[2]; bf16x4 v; };
      UU a0, a1, a2, a3;  // quad r -> keys {0,8,16,24} + 4*hi + 0..3
      a0.u[0] = pk2(p_[0], p_[1]);   a0.u[1] = pk2(p_[2], p_[3]);
      a1.u[0] = pk2(p_[4], p_[5]);   a1.u[1] = pk2(p_[6], p_[7]);
      a2.u[0] = pk2(p_[8], p_[9]);   a2.u[1] = pk2(p_[10], p_[11]);
      a3.u[0] = pk2(p_[12], p_[13]); a3.u[1] = pk2(p_[14], p_[15]);
      const __hip_bfloat16* vb = vbuf + st * 1024 + lq * 8 + hi * 4;
      const bf16x4 vf0 = *reinterpret_cast<const bf16x4*>(vb);        // keys +4hi
      const bf16x4 vf1 = *reinterpret_cast<const bf16x4*>(vb + 256);  // keys +8+4hi
      const bf16x4 vf2 = *reinterpret_cast<const bf16x4*>(vb + 512);  // keys +16+4hi
      const bf16x4 vf3 = *reinterpret_cast<const bf16x4*>(vb + 768);  // keys +24+4hi
      acc0 = __builtin_amdgcn_mfma_f32_32x32x8bf16_1k(a0.v, vf0, acc0, 0, 0, 0);
      acc0 = __builtin_amdgcn_mfma_f32_32x32x8bf16_1k(a1.v, vf1, acc0, 0, 0, 0);
      acc1 = __builtin_amdgcn_mfma_f32_32x32x8bf16_1k(a2.v, vf2, acc1, 0, 0, 0);
      acc1 = __builtin_amdgcn_mfma_f32_32x32x8bf16_1k(a3.v, vf3, acc1, 0, 0, 0);
#else
      unsigned a0u0 = pk2(p_[0], p_[1]),   a0u1 = pk2(p_[2], p_[3]);
      unsigned a1u0 = pk2(p_[4], p_[5]),   a1u1 = pk2(p_[6], p_[7]);
      unsigned a2u0 = pk2(p_[8], p_[9]),   a2u1 = pk2(p_[10], p_[11]);
      unsigned a3u0 = pk2(p_[12], p_[13]), a3u1 = pk2(p_[14], p_[15]);
      union U8 { unsigned u[4]; bf16x8 v; };
      const bf16x8 vh0 = *reinterpret_cast<const bf16x8*>(vbuf + (2 * st) * 512 + lane * 8);
      const bf16x8 vh1 = *reinterpret_cast<const bf16x8*>(vbuf + (2 * st + 1) * 512 + lane * 8);
      {
        const unsigned s0 = __shfl_xor(hi ? a0u0 : a1u0, 32, 64);
        const unsigned s1 = __shfl_xor(hi ? a0u1 : a1u1, 32, 64);
        U8 f;
        f.u[0] = hi ? s0 : a0u0; f.u[1] = hi ? s1 : a0u1;
        f.u[2] = hi ? a1u0 : s0; f.u[3] = hi ? a1u1 : s1;
        acc0 = __builtin_amdgcn_mfma_f32_32x32x16_bf16(f.v, vh0, acc0, 0, 0, 0);
      }
      {
        const unsigned s0 = __shfl_xor(hi ? a2u0 : a3u0, 32, 64);
        const unsigned s1 = __shfl_xor(hi ? a2u1 : a3u1, 32, 64);
        U8 f;
        f.u[0] = hi ? s0 : a2u0; f.u[1] = hi ? s1 : a2u1;
        f.u[2] = hi ? a3u0 : s0; f.u[3] = hi ? a3u1 : s1;
        acc1 = __builtin_amdgcn_mfma_f32_32x32x16_bf16(f.v, vh1, acc1, 0, 0, 0);
      }
#endif
    }
  }

  if (sl == NSL - 1) {
    // tail: 16 real keys (4096..4111), direct from global (L2-hot, tiny)
    const __hip_bfloat16* Kp   = Kt + (size_t)bh * NP * 32 + (size_t)lq * 32 + 8 * hi;
    const __hip_bfloat16* Vrow = Vt + ((size_t)bh * 32 + lq) * NP;
    const int kb = 4096;
    const bf16x8 kf0 = *reinterpret_cast<const bf16x8*>(Kp + (size_t)kb * 32);
    const bf16x8 kf1 = *reinterpret_cast<const bf16x8*>(Kp + (size_t)kb * 32 + 16);
    f32x16 s = __builtin_amdgcn_mfma_f32_32x32x16_bf16(kf0, qf0, z, 0, 0, 0);
    s = __builtin_amdgcn_mfma_f32_32x32x16_bf16(kf1, qf1, s, 0, 0, 0);
    float p_[8];
    #pragma unroll
    for (int r = 0; r < 8; ++r) p_[r] = __builtin_amdgcn_exp2f(s[r]);
    l0 += (p_[0] + p_[1]) + (p_[2] + p_[3]);
    l1 += (p_[4] + p_[5]) + (p_[6] + p_[7]);
#if HAS_PV8
    union UU { unsigned u[2]; bf16x4 v; };
    UU a0, a1;
    a0.u[0] = pk2(p_[0], p_[1]); a0.u[1] = pk2(p_[2], p_[3]);
    a1.u[0] = pk2(p_[4], p_[5]); a1.u[1] = pk2(p_[6], p_[7]);
    const bf16x4 vf0 = *reinterpret_cast<const bf16x4*>(Vrow + kb + 4 * hi);
    const bf16x4 vf1 = *reinterpret_cast<const bf16x4*>(Vrow + kb + 8 + 4 * hi);
    acc0 = __builtin_amdgcn_mfma_f32_32x32x8bf16_1k(a0.v, vf0, acc0, 0, 0, 0);
    acc0 = __builtin_amdgcn_mfma_f32_32x32x8bf16_1k(a1.v, vf1, acc0, 0, 0, 0);
#else
    unsigned a0u0 = pk2(p_[0], p_[1]), a0u1 = pk2(p_[2], p_[3]);
    unsigned a1u0 = pk2(p_[4], p_[5]), a1u1 = pk2(p_[6], p_[7]);
    union U8 { unsigned u[4]; bf16x8 v; };
    const unsigned s0 = __shfl_xor(hi ? a0u0 : a1u0, 32, 64);
    const unsigned s1 = __shfl_xor(hi ? a0u1 : a1u1, 32, 64);
    U8 f;
    f.u[0] = hi ? s0 : a0u0; f.u[1] = hi ? s1 : a0u1;
    f.u[2] = hi ? a1u0 : s0; f.u[3] = hi ? a1u1 : s1;
    const bf16x8 vf = *reinterpret_cast<const bf16x8*>(Vrow + kb + 8 * hi);
    acc0 = __builtin_amdgcn_mfma_f32_32x32x16_bf16(f.v, vf, acc0, 0, 0, 0);
#endif
  }

  // write partials: P[sl][bh][q][d] (d = lq), L[sl][bh][q]
  float* Pp = Pb + (((size_t)sl * 16 + bh) * NQ + qb) * 32;
  #pragma unroll
  for (int r = 0; r < 16; ++r) {
    const int q = (r & 3) + 8 * (r >> 2) + 4 * hi;
    Pp[(size_t)q * 32 + lq] = acc0[r] + acc1[r];
  }
  float lsum = (l0 + l1) + (l2 + l3);       // partial for q = lq (this hi)
  lsum += __shfl_xor(lsum, 32, 64);
  if (hi == 0)
    Lb[((size_t)sl * 16 + bh) * NQ + qb + lq] = lsum;
}

// ---------------- Kernel 2b: combine split-K partials ----------------
// att[bh][q][d] = (sum_s P[s][bh][q][d]) / (sum_s L[s][bh][q])   (bf16)
// grid 2048 x 256: XCD-pinned (reads hit the producing XCD's L2);
// one thread per 4 d-elements.
__global__ __launch_bounds__(256) void k2b_combine(
    const float* __restrict__ Pb, const float* __restrict__ Lb,
    __hip_bfloat16* __restrict__ att) {
  constexpr size_t PS = (size_t)16 * NQ * 32;       // per-slice P elements
  constexpr size_t LS = (size_t)16 * NQ;            // per-slice L elements
  const int wg  = blockIdx.x;          // 0..2047
  const int xcd = wg & 7;
  const int i   = wg >> 3;             // 0..255
  const int bh  = 2 * xcd + (i & 1);   // matches k2's bh->XCD pinning
  const int j   = i >> 1;              // 0..127
  const int u   = j * 256 + threadIdx.x;   // 0..32767 per bh
  const int q   = u >> 3;
  const int d0  = (u & 7) * 4;
  const size_t qi = (size_t)bh * NQ + q;

  float l = 0.f;
  #pragma unroll
  for (int s = 0; s < NSL; ++s) l += Lb[s * LS + qi];
  const float inv = 1.f / l;

  float4 o = make_float4(0.f, 0.f, 0.f, 0.f);
  #pragma unroll
  for (int s = 0; s < NSL; ++s) {
    const float4 f = *reinterpret_cast<const float4*>(Pb + s * PS + qi * 32 + d0);
    o.x += f.x; o.y += f.y; o.z += f.z; o.w += f.w;
  }
  *reinterpret_cast<uint2*>(att + qi * 32 + d0) =
      make_uint2(pk2(o.x * inv, o.y * inv), pk2(o.z * inv, o.w * inv));
}

// ---------------- Kernel 3: output projection ----------------
// grid (128 n-tiles, 4 batches), block 256 (4 waves, 2 o-tiles each).
// att layout is (bh, q, d): head k, d-range 8g..8g+7 for row n.
__global__ __launch_bounds__(256) void k3_proj(
    const __hip_bfloat16* __restrict__ att, const __hip_bfloat16* __restrict__ Wb,
    const float* __restrict__ bout, float* __restrict__ out) {
  const int b = blockIdx.y, nb = blockIdx.x * 32;
  const int wv = threadIdx.x >> 6, lane = threadIdx.x & 63;
  const int li = lane & 15, g = lane >> 4;

  bf16x8 wf[2][4];
  float bo[2][4];
  #pragma unroll
  for (int tt = 0; tt < 2; ++tt) {
    const int ot = 2 * wv + tt;
    #pragma unroll
    for (int k = 0; k < 4; ++k)
      wf[tt][k] = *reinterpret_cast<const bf16x8*>(
          &Wb[(size_t)(ot * 16 + li) * CDIM + k * 32 + 8 * g]);
    #pragma unroll
    for (int r = 0; r < 4; ++r) bo[tt][r] = bout[ot * 16 + 4 * g + r];
  }
  #pragma unroll
  for (int nt = 0; nt < 2; ++nt) {
    bf16x8 bfr[4];
    #pragma unroll
    for (int k = 0; k < 4; ++k)
      bfr[k] = *reinterpret_cast<const bf16x8*>(
          &att[(((size_t)(b * 4 + k)) * NQ + nb + nt * 16 + li) * 32 + 8 * g]);
    #pragma unroll
    for (int tt = 0; tt < 2; ++tt) {
      f32x4 a; a[0] = a[1] = a[2] = a[3] = 0.f;
      #pragma unroll
      for (int k = 0; k < 4; ++k)
        a = __builtin_amdgcn_mfma_f32_16x16x32_bf16(wf[tt][k], bfr[k], a, 0, 0, 0);
      const int ot = 2 * wv + tt;
      #pragma unroll
      for (int r = 0; r < 4; ++r)
        out[((size_t)b * CDIM + ot * 16 + 4 * g + r) * NQ + nb + nt * 16 + li] =
            a[r] + bo[tt][r];
    }
  }
}

extern "C" void kernel_launch(void* const* d_in, const int* in_sizes, int n_in,
                              void* d_out, int out_size, void* d_ws, size_t ws_size,
                              hipStream_t stream) {
  const float* x    = (const float*)d_in[0];
  const float* memp = (const float*)d_in[1];
  const float* wqkv = (const float*)d_in[2];
  const float* wout = (const float*)d_in[3];
  const float* bout = (const float*)d_in[4];
  float* out = (float*)d_out;

  char* ws = (char*)d_ws;
  const size_t SZ  = (size_t)16 * NP * 32 * 2;              // Qt/Kt/Vt each
  const size_t PSZ = (size_t)NSL * 16 * NQ * 32 * 4;        // 33.5 MB
  const size_t LSZ = (size_t)NSL * 16 * NQ * 4;             // 1 MB
  const size_t ASZ = (size_t)16 * NQ * 32 * 2;              // att (bh,q,d) bf16
  __hip_bfloat16* Qt  = (__hip_bfloat16*)(ws);
  __hip_bfloat16* Kt  = (__hip_bfloat16*)(ws + SZ);
  __hip_bfloat16* Vt  = (__hip_bfloat16*)(ws + 2 * SZ);
  float*          Pbf = (float*)(ws + 3 * SZ);
  float*          Lbf = (float*)(ws + 3 * SZ + PSZ);
  __hip_bfloat16* att = (__hip_bfloat16*)(ws + 3 * SZ + PSZ + LSZ);
  __hip_bfloat16* Wb  = (__hip_bfloat16*)(ws + 3 * SZ + PSZ + LSZ + ASZ);

  hipLaunchKernelGGL(k1_qkv, dim3(65, 4, 2), dim3(256), 0, stream,
                     x, memp, wqkv, wout, Qt, Kt, Vt, Wb);
  hipLaunchKernelGGL(k2_attn, dim3(2048), dim3(256), 0, stream,
                     Qt, Kt, Vt, Pbf, Lbf);
  hipLaunchKernelGGL(k2b_combine, dim3(2048), dim3(256), 0, stream, Pbf, Lbf, att);
  hipLaunchKernelGGL(k3_proj, dim3(128, 4), dim3(256), 0, stream, att, Wb, bout, out);
}